// Round 9
// baseline (257.451 us; speedup 1.0000x reference)
//
#include <hip/hip_runtime.h>

// ConvLSTM cell on MI355X (gfx950) — round 12.
// Implicit GEMM M=256 (4 gates x 64 oc), K=864 (96ch x 9 taps), N=131072.
// bf16 MFMA 32x32x16. Wave tile M=64 (og: 4 gates x 16 oc) x N=64 (row y0+nh),
// acc[fi][ns] = 64 AGPR. 512 thr = 8 waves, grid 1024, (512,4), 16 waves/CU.
// Round-12 vs R7 (79.5us): ds_read_b128 was the dominant pipe (6912/CU x
// 12cyc = 43% of wall) because A AND B both came from LDS (1:1 with MFMA).
// Now A NEVER touches LDS: each wave's A-frag is a coalesced 1KB
// global_load_dwordx4 from the L2-resident 432KB a_pk, software-pipelined
// through a depth-3 STATIC register ring (ar[3][2], fully-unrolled 54 phases,
// all indices compile-time -> registers). Compiler inserts counted vmcnt per
// use (R9's failure was a non-unrolled loop: no pipelining window, VGPR=56).
// B staged once into LDS (4 P-rows, 50.7KB, ONE __syncthreads); loop has
// ZERO barriers -> B ds_reads freely hoisted, waves free-run at 16/CU.
// LDS-read traffic halves (only B): floor 17us; MFMA floor 23us.
// Regs: 64 AGPR acc + 24 ring + ~30 work ~ 118 <= 128. Acc order == R7.
// Also: pack_weights + pack_input fused into one pack_all launch
// (blockIdx-partitioned, math identical) - kills one launch gap, overlaps
// latency-bound weight packing with BW-bound input packing.

#define B_   32
#define CIN  32
#define HC_  64
#define HH   64
#define WW   64

#define A_ELEMS (9 * 6 * 8 * 64 * 8)     // 221184 bf16 = 256 x 864 packed A
#define P_ROW   (12 * 66 * 8)            // shorts per P' row = 6336
#define BLDS    (4 * P_ROW)              // 25344 shorts = 50688 B (4 rows)

typedef __attribute__((ext_vector_type(8)))  short  short8;
typedef __attribute__((ext_vector_type(16))) float  floatx16;

struct PackArgs {
    const float* wx[4]; const float* wh[4];
    const float* bx[4]; const float* bh[4];
};

__device__ __forceinline__ short f2bf(float f) {
    unsigned u = __float_as_uint(f);
    u += 0x7FFFu + ((u >> 16) & 1u);     // round-to-nearest-even
    return (short)(u >> 16);
}

__device__ __forceinline__ void gl_lds16(const short* g, short* l) {
    __builtin_amdgcn_global_load_lds(
        (const __attribute__((address_space(1))) unsigned int*)g,
        (__attribute__((address_space(3))) unsigned int*)l, 16, 0, 0);
}

// ---- fused pack: blocks [0,864) pack A+bias, blocks [864,2976) pack x||h ---
// A: [tap 9][kk 6][s 8][lane 64][j 8] ; s = og*2+fi ; m32 = lane&31 ;
// gate = 2*fi + (m32>>4) ; oc = og*16 + (m32&15) ; c = kk*16 + (lane>>5)*8 + j
// P': [b][yy][pc 12][xx 66][8ch] bf16, zero borders.
__global__ __launch_bounds__(256) void pack_all(PackArgs pa, short* a_pk, float* bias,
                                                const float* __restrict__ x,
                                                const float* __restrict__ h,
                                                short* __restrict__ P) {
    __shared__ short t[64 * 98];                     // [x][c], pad 96->98

    if (blockIdx.x < 864) {
        int idx = blockIdx.x * 256 + threadIdx.x;    // < A_ELEMS always
        {
            int j    = idx & 7;
            int lane = (idx >> 3) & 63;
            int rest = idx >> 9;             // (tap*6 + kk)*8 + s
            int s    = rest & 7;
            int rest2 = rest >> 3;
            int kk   = rest2 % 6;
            int tap  = rest2 / 6;
            int og = s >> 1, fi = s & 1;
            int m32 = lane & 31;
            int gate = 2 * fi + (m32 >> 4);
            int oc   = og * 16 + (m32 & 15);
            int c    = kk * 16 + (lane >> 5) * 8 + j;
            int ky = tap / 3, kx = tap - 3 * ky;
            float v = (c < CIN)
                ? pa.wx[gate][((oc * CIN + c) * 3 + ky) * 3 + kx]
                : pa.wh[gate][((oc * HC_ + (c - CIN)) * 3 + ky) * 3 + kx];
            a_pk[idx] = f2bf(v);
        }
        if (idx < 256) {
            int gate = idx >> 6, oc = idx & 63;
            bias[idx] = pa.bx[gate][oc] + pa.bh[gate][oc];
        }
        return;
    }

    const int bb = blockIdx.x - 864;
    const int yy = bb % 66, b = bb / 66;
    int4* prow4 = (int4*)(P + ((size_t)b * 66 + yy) * P_ROW);  // 792 chunks

    if (yy == 0 || yy == 65) {
        int4 z = {0, 0, 0, 0};
        for (int g = threadIdx.x; g < 792; g += 256) prow4[g] = z;
        return;
    }

    const int y = yy - 1;
    const int col = threadIdx.x & 63, cg = threadIdx.x >> 6;
    for (int c = cg; c < 96; c += 4) {
        float v = (c < CIN) ? x[((b * CIN + c) * HH + y) * WW + col]
                            : h[((b * HC_ + (c - CIN)) * HH + y) * WW + col];
        t[col * 98 + c] = f2bf(v);
    }
    __syncthreads();

    for (int g = threadIdx.x; g < 792; g += 256) {   // pc = g/66, xx = g%66
        int pc = g / 66, xx = g - 66 * pc;
        int4 val = {0, 0, 0, 0};
        if (xx >= 1 && xx <= 64) {
            const short* sp = &t[(xx - 1) * 98 + pc * 8];
            val.x = *(const int*)(sp + 0); val.y = *(const int*)(sp + 2);
            val.z = *(const int*)(sp + 4); val.w = *(const int*)(sp + 6);
        }
        prow4[g] = val;
    }
}

// ---- main: grid 1024 = (b 32)x(rowpair 32), 512 thr = 8 waves --------------
// wave = og(0..3) x nh(0..1). acc[fi][ns], 64 AGPR.
// LDS: B only (4 P-rows, staged once). A: depth-3 VGPR ring from global.
// 54 phases (c = tap*6+kk), fully unrolled, NO barriers in the loop.
__global__ __launch_bounds__(512, 4) void convlstm_main(
    const short* __restrict__ P, const short* __restrict__ a_pk,
    const float* __restrict__ bias, const float* __restrict__ cell,
    float* __restrict__ out)
{
    __shared__ __align__(16) short lds[BLDS];        // 50688 B

    const int tid = threadIdx.x;
    const int b  = blockIdx.x >> 5;
    const int y0 = (blockIdx.x & 31) * 2;

    const int wv = tid >> 6, lane = tid & 63;
    const int ln31 = lane & 31, hg = lane >> 5;
    const int og = wv & 3, nh = wv >> 2;
    const int y = y0 + nh;

    floatx16 acc[2][2];
    #pragma unroll
    for (int fi = 0; fi < 2; ++fi)
        #pragma unroll
        for (int ns = 0; ns < 2; ++ns)
            #pragma unroll
            for (int q = 0; q < 16; ++q) acc[fi][ns][q] = 0.f;

    const int b_rd = nh * 6336 + hg * 528 + ln31 * 8;   // + ky*6336+kk*1056+kx*8

    // ---- prologue: stage B rows y0..y0+3 into LDS (3168 chunks / 512 thr)
    {
        const short* Bsrc = P + ((size_t)(b * 66) + y0) * P_ROW;
        #pragma unroll
        for (int i = 0; i < 7; ++i) {
            int id = i * 512 + tid;
            if (id < 3168)
                gl_lds16(Bsrc + id * 8, lds + (i * 512 + wv * 64) * 8);
        }
    }

    // ---- A register pipeline: depth-3 static ring, slots 0..2 preloaded ----
    const short* Ab = a_pk + og * 1024 + lane * 8;   // + c*4096 (+512 for fi=1)
    short8 ar[3][2];
    #pragma unroll
    for (int s = 0; s < 3; ++s) {
        ar[s][0] = *(const short8*)(Ab + s * 4096);
        ar[s][1] = *(const short8*)(Ab + s * 4096 + 512);
    }
    __syncthreads();                                 // the ONLY barrier

    #pragma unroll
    for (int c = 0; c < 54; ++c) {
        const int tap = c / 6, kk = c % 6;
        const int ky = tap / 3, kx = tap % 3;

        short8 a0 = ar[c % 3][0];
        short8 a1 = ar[c % 3][1];
        // refill this slot for phase c+3 (issued before the MFMAs; the
        // compiler's per-use vmcnt gives a 3-phase pipeline window)
        if (c < 51) {
            ar[c % 3][0] = *(const short8*)(Ab + (c + 3) * 4096);
            ar[c % 3][1] = *(const short8*)(Ab + (c + 3) * 4096 + 512);
        }

        const short* Bb = lds + b_rd + ky * 6336 + kk * 1056 + kx * 8;
        short8 b0 = *(const short8*)&Bb[0];
        short8 b1 = *(const short8*)&Bb[256];

        acc[0][0] = __builtin_amdgcn_mfma_f32_32x32x16_bf16(a0, b0, acc[0][0], 0, 0, 0);
        acc[0][1] = __builtin_amdgcn_mfma_f32_32x32x16_bf16(a0, b1, acc[0][1], 0, 0, 0);
        acc[1][0] = __builtin_amdgcn_mfma_f32_32x32x16_bf16(a1, b0, acc[1][0], 0, 0, 0);
        acc[1][1] = __builtin_amdgcn_mfma_f32_32x32x16_bf16(a1, b1, acc[1][1], 0, 0, 0);
    }

    // ---- lane-local LSTM epilogue --------------------------------------
    // C/D 32x32 map: col = ln31, row r32 = (r&3) + 4*hg + 8*(r>>2).
    // acc[fi][.] rows: r32<16 -> gate 2fi, oc16=r32 ; r32>=16 -> gate 2fi+1.
    const size_t plane = (size_t)B_ * HC_ * HH * WW;
    #pragma unroll
    for (int q = 0; q < 4; ++q)
    #pragma unroll
    for (int b8 = 0; b8 < 2; ++b8) {
        const int oc16 = q + 4 * hg + 8 * b8;
        const int oc = og * 16 + oc16;
        const float Bi = bias[oc],       Bf = bias[64 + oc];
        const float Bo = bias[128 + oc], Bg = bias[192 + oc];
        const int r_lo = q + 4 * b8, r_hi = q + 4 * (2 + b8);
        #pragma unroll
        for (int ns = 0; ns < 2; ++ns) {
            float zi = acc[0][ns][r_lo] + Bi;
            float zf = acc[0][ns][r_hi] + Bf;
            float zo = acc[1][ns][r_lo] + Bo;
            float zg = acc[1][ns][r_hi] + Bg;
            float ig = 1.f / (1.f + __expf(-zi));
            float fg = 1.f / (1.f + __expf(-zf));
            float sg = 1.f / (1.f + __expf(-zo));
            float e2 = __expf(2.f * zg);
            float gg = 1.f - 2.f / (e2 + 1.f);               // tanh(zg)
            const int x = ns * 32 + ln31;
            size_t off = ((size_t)(b * HC_ + oc) * HH + y) * WW + x;
            float cn = fg * cell[off] + ig * gg;
            float ec = __expf(2.f * cn);
            out[off] = sg * (1.f - 2.f / (ec + 1.f));        // h_new
            out[plane + off] = cn;                           // c_new
        }
    }
}

extern "C" void kernel_launch(void* const* d_in, const int* in_sizes, int n_in,
                              void* d_out, int out_size, void* d_ws, size_t ws_size,
                              hipStream_t stream) {
    PackArgs pa;
    pa.wx[0] = (const float*)d_in[3];  pa.bx[0] = (const float*)d_in[4];
    pa.wx[1] = (const float*)d_in[5];  pa.bx[1] = (const float*)d_in[6];
    pa.wx[2] = (const float*)d_in[7];  pa.bx[2] = (const float*)d_in[8];
    pa.wx[3] = (const float*)d_in[9];  pa.bx[3] = (const float*)d_in[10];
    pa.wh[0] = (const float*)d_in[11]; pa.bh[0] = (const float*)d_in[12];
    pa.wh[1] = (const float*)d_in[13]; pa.bh[1] = (const float*)d_in[14];
    pa.wh[2] = (const float*)d_in[15]; pa.bh[2] = (const float*)d_in[16];
    pa.wh[3] = (const float*)d_in[17]; pa.bh[3] = (const float*)d_in[18];

    short* a_pk = (short*)d_ws;                                    // 442368 B
    float* bias = (float*)((char*)d_ws + A_ELEMS * sizeof(short)); // 1024 B
    short* P    = (short*)((char*)d_ws + 443392);                  // 26.76 MB

    pack_all<<<dim3(864 + 66 * B_), dim3(256), 0, stream>>>(
        pa, a_pk, bias,
        (const float*)d_in[0], (const float*)d_in[1], P);
    convlstm_main<<<dim3(B_ * 32), dim3(512), 0, stream>>>(
        P, a_pk, bias, (const float*)d_in[2], (float*)d_out);
}